// Round 4
// baseline (21785.924 us; speedup 1.0000x reference)
//
#include <hip/hip_runtime.h>

// N=512 batch, T=256, H=512, D=9. 257 encode + 256 decode steps, LSTM + fc(sigmoid).
// Persistent kernel: 8 clusters x 32 wgs; cluster owns 64 batch, wg owns 16 hidden units.
// W_hh slice resident in LDS (128 KB) for all steps; per-step cluster sync via agent atomics.

#define TT 256
#define HH 512
#define DD 9
#define TP1 257
#define NSTEP 513
#define THREADS 512
#define NWG 256
#define NCL 8
#define WPC 32
#define KC 32
#define NC 16
#define CNT_PAD 520

// ws float offsets
#define WP_OFF 0
#define WP_SZ (2048 * 512)            // Wp[wl 32][k 512][r 64]  (4 MB)
#define HT_OFF WP_SZ                  // hT[2][cl 8][k 512][b 64] (2 MB)
#define HT_HALF (NCL * 512 * 64)
#define HT_SZ (2 * HT_HALF)
#define CNT_OFF (HT_OFF + HT_SZ)      // cnt[8][CNT_PAD] uints

// LDS float offsets (total 38720 floats = 151.25 KB)
#define L_W 0                          // Wlds[k 512][r 64]   128 KB
#define L_UN 32768                     // union: hbuf[2][KC][64] (4096) | gates[64][66] (4224)
#define L_C (L_UN + 4224)              // c[u 16][b 64]
#define L_BIAS (L_C + 1024)            // bias[64]
#define L_WIH (L_BIAS + 64)            // wih[64][10]
#define L_TOT (L_WIH + 640)

#define GSTR 66                        // gates row stride (floats)

__device__ __forceinline__ float sigmoidf_(float v) {
    return 1.0f / (1.0f + __expf(-v));
}
__device__ __forceinline__ float tanhf_(float v) {
    return 1.0f - 2.0f / (__expf(2.0f * v) + 1.0f);
}

// Pack Wp[wl][k][r]: r = g*16+u  <->  W_hh[g*512 + wl*16 + u][k].  Init hT[0] = h0, cnt = 0.
__global__ void rnn_init_kernel(const float* __restrict__ W_hh,
                                const float* __restrict__ h0,
                                float* __restrict__ ws) {
    int idx = blockIdx.x * blockDim.x + threadIdx.x;   // 0 .. 2048*512-1
    {
        int r  = idx & 63;
        int k  = (idx >> 6) & 511;
        int wl = idx >> 15;
        int g = r >> 4, u = r & 15;
        int grow = g * 512 + wl * 16 + u;
        ws[WP_OFF + idx] = W_hh[grow * 512 + k];
    }
    if (idx < HT_HALF) {
        int k = (idx >> 6) & 511;
        ws[HT_OFF + idx] = h0[k];
    }
    if (idx < NCL * CNT_PAD) {
        ((unsigned int*)(ws + CNT_OFF))[idx] = 0u;
    }
}

__global__ __launch_bounds__(THREADS)
void rnn_persist_kernel(const float* __restrict__ x,
                        const float* __restrict__ W_ih,
                        const float* __restrict__ b_ih,
                        const float* __restrict__ b_hh,
                        const float* __restrict__ fc_W,
                        const float* __restrict__ fc_b,
                        const float* __restrict__ c0,
                        float* __restrict__ ws,
                        float* __restrict__ out) {
    __shared__ float smem[L_TOT];

    const int cl  = blockIdx.x & 7;    // cluster (XCD round-robin -> co-located best-effort)
    const int wl  = blockIdx.x >> 3;   // slice within cluster, 0..31
    const int j0  = wl * 16;           // first hidden unit owned
    const int nb0 = cl * 64;           // cluster's batch base
    const int tid = threadIdx.x;

    unsigned int* cnt = (unsigned int*)(ws + CNT_OFF) + cl * CNT_PAD;
    float* hT = ws + HT_OFF;

    // ---- one-time: W slice -> LDS, c from c0, bias, wih ----
    {
        const float* wsrc = ws + WP_OFF + wl * (512 * 64);
        for (int i = tid * 4; i < 512 * 64; i += THREADS * 4)
            *(float4*)(smem + L_W + i) = *(const float4*)(wsrc + i);
        int u = tid >> 6;
        smem[L_C + tid]       = c0[j0 + u];
        smem[L_C + 512 + tid] = c0[j0 + 8 + u];
        if (tid < 64) {
            int g = tid >> 4, u2 = tid & 15;
            int grow = g * 512 + wl * 16 + u2;
            smem[L_BIAS + tid] = b_ih[grow] + b_hh[grow];
        }
        for (int i = tid; i < 64 * DD; i += THREADS) {
            int r = i / DD, d = i - r * DD;
            int g = r >> 4, u2 = r & 15;
            smem[L_WIH + r * 10 + d] = W_ih[(g * 512 + wl * 16 + u2) * DD + d];
        }
    }
    __syncthreads();

    const int tr = tid & 31;           // gemm rows 2tr, 2tr+1
    const int tb = tid >> 5;           // gemm batch 4tb..+3
    const int li_k = tid >> 4;         // staging: k row within chunk
    const int li_b = (tid & 15) * 4;   // staging: batch col
    const int cw = tid >> 6;           // cell: wave id -> unit half
    const int cb = tid & 63;           // cell: batch

    int par = 0;
    for (int s = 0; s < NSTEP; ++s) {
        const float* hsrc = hT + par * HT_HALF + cl * (512 * 64);

        // ===== GEMM: gates[r][b] = sum_k W[r][k] * h[k][b] =====
        float a00 = 0.f, a01 = 0.f, a02 = 0.f, a03 = 0.f;
        float a10 = 0.f, a11 = 0.f, a12 = 0.f, a13 = 0.f;
        float4 rh = *(const float4*)(hsrc + li_k * 64 + li_b);
        for (int c = 0; c < NC; ++c) {
            float4 nh;
            if (c + 1 < NC)
                nh = *(const float4*)(hsrc + ((c + 1) * KC + li_k) * 64 + li_b);
            *(float4*)(smem + L_UN + (c & 1) * (KC * 64) + li_k * 64 + li_b) = rh;
            asm volatile("s_waitcnt lgkmcnt(0)" ::: "memory");
            __builtin_amdgcn_s_barrier();

            const float* hb = smem + L_UN + (c & 1) * (KC * 64) + tb * 4;
            const float* wb = smem + L_W + (c * KC) * 64 + tr * 2;
#pragma unroll
            for (int k = 0; k < KC; ++k) {
                float4 hv = *(const float4*)(hb + k * 64);
                float2 wv = *(const float2*)(wb + k * 64);
                a00 += hv.x * wv.x; a01 += hv.y * wv.x; a02 += hv.z * wv.x; a03 += hv.w * wv.x;
                a10 += hv.x * wv.y; a11 += hv.y * wv.y; a12 += hv.z * wv.y; a13 += hv.w * wv.y;
            }
            rh = nh;
        }
        // union switch: hbuf -> gates
        asm volatile("s_waitcnt lgkmcnt(0)" ::: "memory");
        __builtin_amdgcn_s_barrier();
        *(float4*)(smem + L_UN + (2 * tr) * GSTR + tb * 4)     = make_float4(a00, a01, a02, a03);
        *(float4*)(smem + L_UN + (2 * tr + 1) * GSTR + tb * 4) = make_float4(a10, a11, a12, a13);
        asm volatile("s_waitcnt lgkmcnt(0)" ::: "memory");
        __builtin_amdgcn_s_barrier();

        // ===== LSTM cell: thread owns units {cw, cw+8} for batch cb =====
        {
            const bool enc = (s < TP1);
            float xv[DD];
            if (enc) {
                const float* xp = x + (size_t)(nb0 + cb) * (TP1 * DD) + s * DD;
#pragma unroll
                for (int d = 0; d < DD; ++d) xv[d] = xp[d];
            }
            float* hdst = hT + (par ^ 1) * HT_HALF + cl * (512 * 64);
#pragma unroll
            for (int half = 0; half < 2; ++half) {
                int u = cw + half * 8;
                float vi = smem[L_UN + (u) * GSTR + cb]      + smem[L_BIAS + u];
                float vf = smem[L_UN + (16 + u) * GSTR + cb] + smem[L_BIAS + 16 + u];
                float vg = smem[L_UN + (32 + u) * GSTR + cb] + smem[L_BIAS + 32 + u];
                float vo = smem[L_UN + (48 + u) * GSTR + cb] + smem[L_BIAS + 48 + u];
                if (enc) {
                    float di = 0.f, df = 0.f, dg = 0.f, dq = 0.f;
#pragma unroll
                    for (int d = 0; d < DD; ++d) {
                        di += xv[d] * smem[L_WIH + (u) * 10 + d];
                        df += xv[d] * smem[L_WIH + (16 + u) * 10 + d];
                        dg += xv[d] * smem[L_WIH + (32 + u) * 10 + d];
                        dq += xv[d] * smem[L_WIH + (48 + u) * 10 + d];
                    }
                    vi += di; vf += df; vg += dg; vo += dq;
                }
                float c_old = smem[L_C + u * 64 + cb];
                float si = sigmoidf_(vi), sf = sigmoidf_(vf), so = sigmoidf_(vo);
                float tg = tanhf_(vg);
                float cn = sf * c_old + si * tg;
                smem[L_C + u * 64 + cb] = cn;
                hdst[(j0 + u) * 64 + cb] = so * tanhf_(cn);
            }
        }
        __syncthreads();   // drains vmcnt: all h stores of this wg complete

        // ===== cluster sync =====
        if (tid == 0) {
            __hip_atomic_fetch_add(cnt + s, 1u, __ATOMIC_RELEASE,
                                   __HIP_MEMORY_SCOPE_AGENT);
            while (__hip_atomic_load(cnt + s, __ATOMIC_RELAXED,
                                     __HIP_MEMORY_SCOPE_AGENT) < WPC) {
                __builtin_amdgcn_s_sleep(2);
            }
        }
        __syncthreads();
        __builtin_amdgcn_fence(__ATOMIC_ACQUIRE, "agent");

        // ===== fc output (decode steps): out[:, s-257, :] from h after step s =====
        if (s >= TP1) {
            int wq = tid >> 4, l16 = tid & 15;
            if (wq < 2 * DD) {
                int bsel = wq / DD, d = wq - bsel * DD;
                int bl = wl * 2 + bsel;
                const float* hv2 = hT + (par ^ 1) * HT_HALF + cl * (512 * 64) + bl;
                float acc = 0.f;
#pragma unroll 8
                for (int k = l16; k < HH; k += 16)
                    acc += hv2[k * 64] * fc_W[d * HH + k];
                acc += __shfl_down(acc, 8, 16);
                acc += __shfl_down(acc, 4, 16);
                acc += __shfl_down(acc, 2, 16);
                acc += __shfl_down(acc, 1, 16);
                if (l16 == 0) {
                    out[(size_t)(nb0 + bl) * (TT * DD) + (s - TP1) * DD + d] =
                        1.0f / (1.0f + __expf(-(acc + fc_b[d])));
                }
            }
        }
        par ^= 1;
    }
}

extern "C" void kernel_launch(void* const* d_in, const int* in_sizes, int n_in,
                              void* d_out, int out_size, void* d_ws, size_t ws_size,
                              hipStream_t stream) {
    (void)in_sizes; (void)n_in; (void)out_size; (void)ws_size;
    const float* x    = (const float*)d_in[0];
    const float* W_ih = (const float*)d_in[1];
    const float* W_hh = (const float*)d_in[2];
    const float* b_ih = (const float*)d_in[3];
    const float* b_hh = (const float*)d_in[4];
    const float* fc_W = (const float*)d_in[5];
    const float* fc_b = (const float*)d_in[6];
    const float* h0   = (const float*)d_in[7];
    const float* c0   = (const float*)d_in[8];
    float* out = (float*)d_out;
    float* ws  = (float*)d_ws;

    hipLaunchKernelGGL(rnn_init_kernel, dim3(4096), dim3(256), 0, stream,
                       W_hh, h0, ws);
    hipLaunchKernelGGL(rnn_persist_kernel, dim3(NWG), dim3(THREADS), 0, stream,
                       x, W_ih, b_ih, b_hh, fc_W, fc_b, c0, ws, out);
}